// Round 10
// baseline (644.562 us; speedup 1.0000x reference)
//
#include <hip/hip_runtime.h>

// 2-layer LSTM encoder, B=128, T=1024, F=1, HID=128, EMB=64.
// R19 = R18 (split-CU chunked pipeline, verified: absmax bit-exact, 568us)
// with producer-tail compression. Producer step was 1332cy vs a 620cy
// matrix-pipe floor; ~710cy tail. Diagnosis: the if(l<16) branch around the
// elementwise block is an s_cbranch_execz scheduling WALL -- all 16 MFMAs
// issue, then the ~150-200cy sigmoid/tanh chain runs with the matrix pipe
// idle (both co-SIMD waves in lockstep).
// Changes (producer only; consumer + handoff protocol byte-identical):
//   1. ew UNMASKED: A-rows are replicated, so acc[g][0] on every lane holds
//      the gate value for col l&15 -- lanes 16-63 compute valid duplicates.
//      Same issue cost as masked, but deletes the branch wall: scheduler can
//      interleave trans-pipe ew with matrix-pipe MFMA issue. Only ds_write +
//      ring store stay masked (l<16): one writer per cell, numerics identical
//      (upper-lane c1 is self-consistent garbage after step 0, never read).
//   2. per-gate source clusters: gate g's 4 MFMAs then its activation;
//      c1-chain + tanh(c1) between gate-3 MFMA issue and consumption.
//   3. ring offset (s&63)*128 (== ((s>>3)&7)*1024+(s&7)*128, fewer VALU).
// Protocol recap (R18-verified): chunk=8 steps, flag published 2 steps late
// after s_waitcnt vmcnt(2); back-pressure once per chunk (consFlag >= C-7);
// RAWBAR (lgkmcnt-only barrier) per step so ring stores stay in flight;
// consumer stages chunks via wave 4 into SH1 dbuf. All polls bounded.
// Correctness gate: absmax exactly 4.882812e-4.

#define TB   1024
#define HID1 128
#define EMB2 64

typedef _Float16 f16x8 __attribute__((ext_vector_type(8)));
typedef float    f32x4 __attribute__((ext_vector_type(4)));

#define MFMA16(a,b,c) __builtin_amdgcn_mfma_f32_16x16x32_f16((a),(b),(c),0,0,0)

static __device__ __forceinline__ float fast_exp2(float x){
#if __has_builtin(__builtin_amdgcn_exp2f)
  return __builtin_amdgcn_exp2f(x);
#else
  return __exp2f(x);
#endif
}
static __device__ __forceinline__ float fast_rcp(float x){
#if __has_builtin(__builtin_amdgcn_rcpf)
  return __builtin_amdgcn_rcpf(x);
#else
  return 1.0f / x;
#endif
}
static __device__ __forceinline__ float sigmoid_f(float x){
  return fast_rcp(1.0f + fast_exp2(-1.44269504088896340736f * x));
}
static __device__ __forceinline__ float tanh_f(float x){
  return 1.0f - 2.0f * fast_rcp(1.0f + fast_exp2(2.88539008177792681472f * x));
}

static __device__ __forceinline__ f16x8 load_frag(const float* p){
  f16x8 r;
  #pragma unroll
  for (int j = 0; j < 8; ++j) r[j] = (_Float16)p[j];
  return r;
}

// Barrier without vmcnt drain (global stores stay in flight).
#define RAWBAR() do {                                          \
    asm volatile("s_waitcnt lgkmcnt(0)" ::: "memory");         \
    __builtin_amdgcn_s_barrier();                              \
    __builtin_amdgcn_sched_barrier(0);                         \
  } while(0)

__launch_bounds__(512, 1)
__global__ void lstm2_kernel(const float* __restrict__ x,
                             const float* __restrict__ w_ih1,
                             const float* __restrict__ w_hh1,
                             const float* __restrict__ b_ih1,
                             const float* __restrict__ b_hh1,
                             const float* __restrict__ w_ih2,
                             const float* __restrict__ w_hh2,
                             const float* __restrict__ b_ih2,
                             const float* __restrict__ b_hh2,
                             float* __restrict__ out,
                             unsigned* __restrict__ ws)
{
  __shared__ __align__(16) float    xs[TB];            // producer
  __shared__ __align__(16) _Float16 H1R[8][HID1];      // producer h1 ring
  __shared__ __align__(16) _Float16 SH1[2][8][HID1];   // consumer staged h1 (dbuf)
  __shared__ __align__(16) _Float16 H2R[8][EMB2];      // consumer h2 ring
  __shared__ unsigned readyUpTo;                       // consumer chunk gate

  const int t    = threadIdx.x;   // 0..511
  const int l    = t & 63;
  const int w    = t >> 6;        // wave 0..7
  const int col  = l & 15;
  const int quad = l >> 4;

  unsigned* prodFlag = ws;          // [128] chunks published
  unsigned* consFlag = ws + 128;    // [128] chunks consumed
  unsigned* ring     = ws + 256;    // [128][8][8][128] f32 bits

  const f32x4 zacc = {0.0f, 0.0f, 0.0f, 0.0f};

  if (blockIdx.x < 128){
    // ===================== L1 PRODUCER (batch bb) =====================
    const int bb = blockIdx.x;
    f16x8 B1[16];                    // [g][k] flattened
    float biasA[4], wxA[4];
    #pragma unroll
    for (int g = 0; g < 4; ++g){
      const int nA = (w + 8*g)*16 + col;
      biasA[g] = b_ih1[nA] + b_hh1[nA];
      wxA[g]   = w_ih1[nA];                    // w_ih1 is (512,1)
      #pragma unroll
      for (int k = 0; k < 4; ++k)
        B1[4*g + k] = load_frag(w_hh1 + nA*HID1 + k*32 + quad*8);
    }
    xs[t]       = x[bb * TB + t];
    xs[t + 512] = x[bb * TB + t + 512];
    __syncthreads();

    float c1 = 0.0f;
    const int cellA = 16*w + l;                 // valid when l<16
    const unsigned ringBase = (unsigned)bb*8192u + (unsigned)cellA;

    // step 0: h1(0) = f(x0), no MFMA. Compute unmasked, write masked.
    {
      const float xt = xs[0];
      const float a0 = sigmoid_f(__builtin_fmaf(xt, wxA[0], biasA[0]));
      const float a1 = sigmoid_f(__builtin_fmaf(xt, wxA[1], biasA[1]));
      const float a2 = tanh_f  (__builtin_fmaf(xt, wxA[2], biasA[2]));
      const float a3 = sigmoid_f(__builtin_fmaf(xt, wxA[3], biasA[3]));
      c1 = a1 * c1 + a0 * a2;
      const float hv = a3 * tanh_f(c1);
      if (l < 16){
        H1R[0][cellA] = (_Float16)hv;
        __hip_atomic_store(&ring[ringBase],
                           __float_as_uint(hv),
                           __ATOMIC_RELAXED, __HIP_MEMORY_SCOPE_AGENT);
      }
    }

    unsigned cachedCons = 0;
    #pragma unroll 1
    for (int s = 1; s < TB; ++s){
      const bool pub = ((s & 7) == 2) && (s >= 10);
      if (pub) asm volatile("s_waitcnt vmcnt(2)" ::: "memory");  // chunk retired
      RAWBAR();
      if (pub && w == 0 && l == 0)
        __hip_atomic_store(&prodFlag[bb], (unsigned)(((s - 10) >> 3) + 1),
                           __ATOMIC_RELAXED, __HIP_MEMORY_SCOPE_AGENT);
      if (((s & 7) == 0) && s >= 64){
        // back-pressure: about to overwrite ring slot (s>>3)&7 (chunk C-8)
        if (w == 0 && l == 0){
          const unsigned need = (unsigned)((s >> 3) - 7);
          if (cachedCons < need){
            int gd = 0;
            while (cachedCons < need && gd++ < (1 << 20)){
              cachedCons = __hip_atomic_load(&consFlag[bb], __ATOMIC_ACQUIRE,
                                             __HIP_MEMORY_SCOPE_AGENT);
              if (cachedCons < need) __builtin_amdgcn_s_sleep(2);
            }
          }
        }
        RAWBAR();   // hold all waves until wave 0 clears back-pressure
      }

      const f16x8* pA1 = (const f16x8*)&H1R[(s-1)&7][0];
      const f16x8 a10 = pA1[quad],     a12 = pA1[8+quad],
                  a11 = pA1[4+quad],   a13 = pA1[12+quad];
      const float xt = xs[s];

      // ---- per-gate clusters: MFMAs then that gate's activation (unmasked;
      //      all lanes hold col l&15's value since A-rows are replicated) ----
      float act0, act1, act2;
      {
        f32x4 lo = MFMA16(a10, B1[0],  zacc);
        f32x4 hi = MFMA16(a12, B1[2],  zacc);
        lo = MFMA16(a11, B1[1],  lo);
        hi = MFMA16(a13, B1[3],  hi);
        act0 = sigmoid_f(lo[0] + hi[0] + __builtin_fmaf(xt, wxA[0], biasA[0]));
      }
      {
        f32x4 lo = MFMA16(a10, B1[4],  zacc);
        f32x4 hi = MFMA16(a12, B1[6],  zacc);
        lo = MFMA16(a11, B1[5],  lo);
        hi = MFMA16(a13, B1[7],  hi);
        act1 = sigmoid_f(lo[0] + hi[0] + __builtin_fmaf(xt, wxA[1], biasA[1]));
      }
      {
        f32x4 lo = MFMA16(a10, B1[8],  zacc);
        f32x4 hi = MFMA16(a12, B1[10], zacc);
        lo = MFMA16(a11, B1[9],  lo);
        hi = MFMA16(a13, B1[11], hi);
        act2 = tanh_f(lo[0] + hi[0] + __builtin_fmaf(xt, wxA[2], biasA[2]));
      }
      // gate 3: issue MFMAs first, run the c1 chain under them
      f32x4 lo3 = MFMA16(a10, B1[12], zacc);
      f32x4 hi3 = MFMA16(a12, B1[14], zacc);
      lo3 = MFMA16(a11, B1[13], lo3);
      hi3 = MFMA16(a13, B1[15], hi3);
      c1 = act1 * c1 + act0 * act2;
      const float tc = tanh_f(c1);
      const float act3 = sigmoid_f(lo3[0] + hi3[0] +
                                   __builtin_fmaf(xt, wxA[3], biasA[3]));
      const float hv = act3 * tc;

      if (l < 16){
        H1R[s&7][cellA] = (_Float16)hv;
        __hip_atomic_store(&ring[ringBase + (unsigned)((s & 63) << 7)],
                           __float_as_uint(hv),
                           __ATOMIC_RELAXED, __HIP_MEMORY_SCOPE_AGENT);
      }
    }
    // final: drain everything, publish chunk 127 (flag = 128)
    asm volatile("s_waitcnt vmcnt(0)" ::: "memory");
    RAWBAR();
    if (w == 0 && l == 0)
      __hip_atomic_store(&prodFlag[bb], 128u,
                         __ATOMIC_RELEASE, __HIP_MEMORY_SCOPE_AGENT);

  } else {
    // ===================== L2 CONSUMER (batch bb) — R18 verbatim ==========
    const int bb = blockIdx.x - 128;
    f16x8 B2i[16], B2h[8];
    float biasB[4] = {0,0,0,0};
    if (w < 4){
      #pragma unroll
      for (int g = 0; g < 4; ++g){
        const int nB = (4*g + w)*16 + col;
        biasB[g] = b_ih2[nB] + b_hh2[nB];
        #pragma unroll
        for (int k = 0; k < 4; ++k)
          B2i[4*g + k] = load_frag(w_ih2 + nB*HID1 + k*32 + quad*8);
        #pragma unroll
        for (int k = 0; k < 2; ++k)
          B2h[2*g + k] = load_frag(w_hh2 + nB*EMB2 + k*32 + quad*8);
      }
    }
    if (t < EMB2) H2R[7][t] = (_Float16)0.0f;   // h2(-1) = 0
    if (t == 0) readyUpTo = 0u;
    __syncthreads();

    unsigned staged = 0;   // stager (wave 4) private progress
    float c2 = 0.0f;

    #define STAGE_ATTEMPT() do {                                              \
        if (staged < 128u){                                                   \
          const unsigned pf_ = __hip_atomic_load(&prodFlag[bb],               \
                                  __ATOMIC_ACQUIRE, __HIP_MEMORY_SCOPE_AGENT);\
          asm volatile("" ::: "memory");                                      \
          __builtin_amdgcn_sched_barrier(0);                                  \
          if (pf_ > staged){                                                  \
            const float4* rp_ = (const float4*)(ring                          \
                + (unsigned)(bb*8 + (staged&7))*1024u + (unsigned)l*16u);     \
            const float4 v0_ = rp_[0], v1_ = rp_[1],                          \
                         v2_ = rp_[2], v3_ = rp_[3];                          \
            f16x8 p0_, p1_;                                                   \
            p0_[0]=(_Float16)v0_.x; p0_[1]=(_Float16)v0_.y;                   \
            p0_[2]=(_Float16)v0_.z; p0_[3]=(_Float16)v0_.w;                   \
            p0_[4]=(_Float16)v1_.x; p0_[5]=(_Float16)v1_.y;                   \
            p0_[6]=(_Float16)v1_.z; p0_[7]=(_Float16)v1_.w;                   \
            p1_[0]=(_Float16)v2_.x; p1_[1]=(_Float16)v2_.y;                   \
            p1_[2]=(_Float16)v2_.z; p1_[3]=(_Float16)v2_.w;                   \
            p1_[4]=(_Float16)v3_.x; p1_[5]=(_Float16)v3_.y;                   \
            p1_[6]=(_Float16)v3_.z; p1_[7]=(_Float16)v3_.w;                   \
            f16x8* dst_ = (f16x8*)&SH1[staged&1][0][0];                       \
            dst_[2*l] = p0_; dst_[2*l+1] = p1_;                               \
            asm volatile("" ::: "memory");                                    \
            if (l == 0){                                                      \
              __hip_atomic_store(&consFlag[bb], staged + 1u,                  \
                  __ATOMIC_RELAXED, __HIP_MEMORY_SCOPE_AGENT);                \
              readyUpTo = staged + 1u;                                        \
            }                                                                 \
            staged++;                                                         \
          }                                                                   \
        }                                                                     \
      } while(0)

    #pragma unroll 1
    for (int m = 0; m < TB; ++m){
      const int c = m >> 3;
      if ((m & 7) == 0){
        int gd = 0;
        while (*(volatile unsigned*)&readyUpTo < (unsigned)(c + 1)
               && gd++ < (1 << 20)){
          if (w == 4) STAGE_ATTEMPT();
          __syncthreads();
        }
        if (w == 4) STAGE_ATTEMPT();   // opportunistic prefetch of chunk c+1
      }

      if (w < 4){
        const f16x8* pA2 = (const f16x8*)&H2R[(m+7)&7][0];     // h2(m-1)
        const f16x8 a20 = pA2[quad], a21 = pA2[4+quad];
        const f16x8* pA1 = (const f16x8*)&SH1[c&1][m&7][0];    // staged h1(m)
        const f16x8 a10 = pA1[quad],    a11 = pA1[4+quad],
                    a12 = pA1[8+quad],  a13 = pA1[12+quad];
        f32x4 lo[4], hi[4];
        #pragma unroll
        for (int g = 0; g < 4; ++g){
          lo[g] = MFMA16(a10, B2i[4*g+0], zacc);
          hi[g] = MFMA16(a12, B2i[4*g+2], zacc);
        }
        #pragma unroll
        for (int g = 0; g < 4; ++g){
          lo[g] = MFMA16(a11, B2i[4*g+1], lo[g]);
          hi[g] = MFMA16(a13, B2i[4*g+3], hi[g]);
        }
        #pragma unroll
        for (int g = 0; g < 4; ++g){
          lo[g] = MFMA16(a20, B2h[2*g+0], lo[g]);
          hi[g] = MFMA16(a21, B2h[2*g+1], hi[g]);
        }
        if (l < 16){
          float g4[4];
          #pragma unroll
          for (int g = 0; g < 4; ++g) g4[g] = lo[g][0] + hi[g][0] + biasB[g];
          c2 = sigmoid_f(g4[1]) * c2 + sigmoid_f(g4[0]) * tanh_f(g4[2]);
          const float hv = sigmoid_f(g4[3]) * tanh_f(c2);
          if (m < TB-1) H2R[m&7][16*w + l] = (_Float16)hv;
          else          out[bb * EMB2 + 16*w + l] = hv;
        }
      }
      __syncthreads();
    }
    #undef STAGE_ATTEMPT
  }
}

extern "C" void kernel_launch(void* const* d_in, const int* in_sizes, int n_in,
                              void* d_out, int out_size, void* d_ws, size_t ws_size,
                              hipStream_t stream) {
  // zero the 256 flag counters each launch (stream-ordered, graph-capturable)
  hipMemsetAsync(d_ws, 0, 256 * sizeof(unsigned), stream);
  lstm2_kernel<<<dim3(256), dim3(512), 0, stream>>>(
      (const float*)d_in[0],   // x
      (const float*)d_in[1],   // w_ih1
      (const float*)d_in[2],   // w_hh1
      (const float*)d_in[3],   // b_ih1
      (const float*)d_in[4],   // b_hh1
      (const float*)d_in[5],   // w_ih2
      (const float*)d_in[6],   // w_hh2
      (const float*)d_in[7],   // b_ih2
      (const float*)d_in[8],   // b_hh2
      (float*)d_out,
      (unsigned*)d_ws);
}

// Round 11
// 573.520 us; speedup vs baseline: 1.1239x; 1.1239x over previous
//
#include <hip/hip_runtime.h>

// 2-layer LSTM encoder, B=128, T=1024, F=1, HID=128, EMB=64.
// R20 = revert to R18 (proven 568us steady, absmax bit-exact) + 2 micro-trims.
//   R19 post-mortem: per-gate MFMA clustering REGRESSED 568->633us. The
//   if(l<16) "branch wall" theory was wrong (every wave has active lanes in
//   l<16 -> execz never fires; compiler could already interleave). R19's real
//   change was dependency structure: 4x dependent-result stalls per step
//   (one per gate cluster) vs R18's single stall after 8-heads-then-8-deps.
//   LESSON: R18's MFMA grouping (8 independent heads, then 8 deps) is
//   load-bearing. Do not restructure it.
// Micro-trims vs R18 (both zero-risk):
//   1. ds_read of a1 hoisted to right after the first RAWBAR, above the
//      pub-flag store and chunk-boundary back-pressure block. RAWBAR's
//      sched_barrier(0) blocks motion, so in R18 these loads were trapped
//      below the back-pressure barrier on 1/8 steps. Reading slot (s-1)&7
//      before the back-pressure barrier is safe (it only protects the
//      overwrite of slot s&7).
//   2. ring offset = ringBase + ((s&63)<<7) (identity, proven bit-exact R19).
// Protocol (R18-verified): chunk=8 steps; prodFlag published 2 steps late
// after s_waitcnt vmcnt(2); back-pressure once per chunk (consFlag >= C-7);
// RAWBAR (lgkmcnt-only barrier) per step so ring stores stay in flight;
// consumer wave 4 stages chunks into SH1 dbuf; all polls bounded.
// Correctness gate: absmax exactly 4.882812e-4.

#define TB   1024
#define HID1 128
#define EMB2 64

typedef _Float16 f16x8 __attribute__((ext_vector_type(8)));
typedef float    f32x4 __attribute__((ext_vector_type(4)));

#define MFMA16(a,b,c) __builtin_amdgcn_mfma_f32_16x16x32_f16((a),(b),(c),0,0,0)

static __device__ __forceinline__ float fast_exp2(float x){
#if __has_builtin(__builtin_amdgcn_exp2f)
  return __builtin_amdgcn_exp2f(x);
#else
  return __exp2f(x);
#endif
}
static __device__ __forceinline__ float fast_rcp(float x){
#if __has_builtin(__builtin_amdgcn_rcpf)
  return __builtin_amdgcn_rcpf(x);
#else
  return 1.0f / x;
#endif
}
static __device__ __forceinline__ float sigmoid_f(float x){
  return fast_rcp(1.0f + fast_exp2(-1.44269504088896340736f * x));
}
static __device__ __forceinline__ float tanh_f(float x){
  return 1.0f - 2.0f * fast_rcp(1.0f + fast_exp2(2.88539008177792681472f * x));
}

static __device__ __forceinline__ f16x8 load_frag(const float* p){
  f16x8 r;
  #pragma unroll
  for (int j = 0; j < 8; ++j) r[j] = (_Float16)p[j];
  return r;
}

// Barrier without vmcnt drain (global stores stay in flight).
#define RAWBAR() do {                                          \
    asm volatile("s_waitcnt lgkmcnt(0)" ::: "memory");         \
    __builtin_amdgcn_s_barrier();                              \
    __builtin_amdgcn_sched_barrier(0);                         \
  } while(0)

__launch_bounds__(512, 1)
__global__ void lstm2_kernel(const float* __restrict__ x,
                             const float* __restrict__ w_ih1,
                             const float* __restrict__ w_hh1,
                             const float* __restrict__ b_ih1,
                             const float* __restrict__ b_hh1,
                             const float* __restrict__ w_ih2,
                             const float* __restrict__ w_hh2,
                             const float* __restrict__ b_ih2,
                             const float* __restrict__ b_hh2,
                             float* __restrict__ out,
                             unsigned* __restrict__ ws)
{
  __shared__ __align__(16) float    xs[TB];            // producer
  __shared__ __align__(16) _Float16 H1R[8][HID1];      // producer h1 ring
  __shared__ __align__(16) _Float16 SH1[2][8][HID1];   // consumer staged h1 (dbuf)
  __shared__ __align__(16) _Float16 H2R[8][EMB2];      // consumer h2 ring
  __shared__ unsigned readyUpTo;                       // consumer chunk gate

  const int t    = threadIdx.x;   // 0..511
  const int l    = t & 63;
  const int w    = t >> 6;        // wave 0..7
  const int col  = l & 15;
  const int quad = l >> 4;

  unsigned* prodFlag = ws;          // [128] chunks published
  unsigned* consFlag = ws + 128;    // [128] chunks consumed
  unsigned* ring     = ws + 256;    // [128][8][8][128] f32 bits

  const f32x4 zacc = {0.0f, 0.0f, 0.0f, 0.0f};

  if (blockIdx.x < 128){
    // ===================== L1 PRODUCER (batch bb) =====================
    const int bb = blockIdx.x;
    f16x8 B1[16];                    // [g][k] flattened
    float biasA[4], wxA[4];
    #pragma unroll
    for (int g = 0; g < 4; ++g){
      const int nA = (w + 8*g)*16 + col;
      biasA[g] = b_ih1[nA] + b_hh1[nA];
      wxA[g]   = w_ih1[nA];                    // w_ih1 is (512,1)
      #pragma unroll
      for (int k = 0; k < 4; ++k)
        B1[4*g + k] = load_frag(w_hh1 + nA*HID1 + k*32 + quad*8);
    }
    xs[t]       = x[bb * TB + t];
    xs[t + 512] = x[bb * TB + t + 512];
    __syncthreads();

    float c1 = 0.0f;
    const int cellA = 16*w + l;                 // valid when l<16
    const unsigned ringBase = (unsigned)bb*8192u + (unsigned)cellA;

    // step 0: h1(0) = f(x0), no MFMA
    if (l < 16){
      const float xt = xs[0];
      float g4[4];
      #pragma unroll
      for (int g = 0; g < 4; ++g) g4[g] = __builtin_fmaf(xt, wxA[g], biasA[g]);
      c1 = sigmoid_f(g4[1]) * c1 + sigmoid_f(g4[0]) * tanh_f(g4[2]);
      const float hv = sigmoid_f(g4[3]) * tanh_f(c1);
      H1R[0][cellA] = (_Float16)hv;
      __hip_atomic_store(&ring[ringBase],
                         __float_as_uint(hv),
                         __ATOMIC_RELAXED, __HIP_MEMORY_SCOPE_AGENT);
    }

    unsigned cachedCons = 0;
    #pragma unroll 1
    for (int s = 1; s < TB; ++s){
      const bool pub = ((s & 7) == 2) && (s >= 10);
      if (pub) asm volatile("s_waitcnt vmcnt(2)" ::: "memory");  // chunk retired
      RAWBAR();

      // ---- a1 fragment loads issued IMMEDIATELY at barrier release (trim 1;
      //      slot (s-1)&7, safe before the back-pressure barrier) ----
      const f16x8* pA1 = (const f16x8*)&H1R[(s-1)&7][0];
      const f16x8 a10 = pA1[quad],     a11 = pA1[4+quad],
                  a12 = pA1[8+quad],   a13 = pA1[12+quad];

      if (pub && w == 0 && l == 0)
        __hip_atomic_store(&prodFlag[bb], (unsigned)(((s - 10) >> 3) + 1),
                           __ATOMIC_RELAXED, __HIP_MEMORY_SCOPE_AGENT);
      if (((s & 7) == 0) && s >= 64){
        // back-pressure: about to overwrite ring slot (s>>3)&7 (chunk C-8)
        if (w == 0 && l == 0){
          const unsigned need = (unsigned)((s >> 3) - 7);
          if (cachedCons < need){
            int gd = 0;
            while (cachedCons < need && gd++ < (1 << 20)){
              cachedCons = __hip_atomic_load(&consFlag[bb], __ATOMIC_ACQUIRE,
                                             __HIP_MEMORY_SCOPE_AGENT);
              if (cachedCons < need) __builtin_amdgcn_s_sleep(2);
            }
          }
        }
        RAWBAR();   // hold all waves until wave 0 clears back-pressure
      }

      // ---- R18-verified MFMA shape: 8 independent heads, then 8 deps ----
      f32x4 aLo[4], aHi[4];
      #pragma unroll
      for (int g = 0; g < 4; ++g){
        aLo[g] = MFMA16(a10, B1[4*g+0], zacc);
        aHi[g] = MFMA16(a12, B1[4*g+2], zacc);
      }
      #pragma unroll
      for (int g = 0; g < 4; ++g){
        aLo[g] = MFMA16(a11, B1[4*g+1], aLo[g]);
        aHi[g] = MFMA16(a13, B1[4*g+3], aHi[g]);
      }
      if (l < 16){
        float g4[4];
        #pragma unroll
        for (int g = 0; g < 4; ++g)
          g4[g] = aLo[g][0] + aHi[g][0] + __builtin_fmaf(xs[s], wxA[g], biasA[g]);
        c1 = sigmoid_f(g4[1]) * c1 + sigmoid_f(g4[0]) * tanh_f(g4[2]);
        const float hv = sigmoid_f(g4[3]) * tanh_f(c1);
        H1R[s&7][cellA] = (_Float16)hv;
        __hip_atomic_store(&ring[ringBase + (unsigned)((s & 63) << 7)],
                           __float_as_uint(hv),
                           __ATOMIC_RELAXED, __HIP_MEMORY_SCOPE_AGENT);
      }
    }
    // final: drain everything, publish chunk 127 (flag = 128)
    asm volatile("s_waitcnt vmcnt(0)" ::: "memory");
    RAWBAR();
    if (w == 0 && l == 0)
      __hip_atomic_store(&prodFlag[bb], 128u,
                         __ATOMIC_RELEASE, __HIP_MEMORY_SCOPE_AGENT);

  } else {
    // ===================== L2 CONSUMER (batch bb) — R18 verbatim ==========
    const int bb = blockIdx.x - 128;
    f16x8 B2i[16], B2h[8];
    float biasB[4] = {0,0,0,0};
    if (w < 4){
      #pragma unroll
      for (int g = 0; g < 4; ++g){
        const int nB = (4*g + w)*16 + col;
        biasB[g] = b_ih2[nB] + b_hh2[nB];
        #pragma unroll
        for (int k = 0; k < 4; ++k)
          B2i[4*g + k] = load_frag(w_ih2 + nB*HID1 + k*32 + quad*8);
        #pragma unroll
        for (int k = 0; k < 2; ++k)
          B2h[2*g + k] = load_frag(w_hh2 + nB*EMB2 + k*32 + quad*8);
      }
    }
    if (t < EMB2) H2R[7][t] = (_Float16)0.0f;   // h2(-1) = 0
    if (t == 0) readyUpTo = 0u;
    __syncthreads();

    unsigned staged = 0;   // stager (wave 4) private progress
    float c2 = 0.0f;

    #define STAGE_ATTEMPT() do {                                              \
        if (staged < 128u){                                                   \
          const unsigned pf_ = __hip_atomic_load(&prodFlag[bb],               \
                                  __ATOMIC_ACQUIRE, __HIP_MEMORY_SCOPE_AGENT);\
          asm volatile("" ::: "memory");                                      \
          __builtin_amdgcn_sched_barrier(0);                                  \
          if (pf_ > staged){                                                  \
            const float4* rp_ = (const float4*)(ring                          \
                + (unsigned)(bb*8 + (staged&7))*1024u + (unsigned)l*16u);     \
            const float4 v0_ = rp_[0], v1_ = rp_[1],                          \
                         v2_ = rp_[2], v3_ = rp_[3];                          \
            f16x8 p0_, p1_;                                                   \
            p0_[0]=(_Float16)v0_.x; p0_[1]=(_Float16)v0_.y;                   \
            p0_[2]=(_Float16)v0_.z; p0_[3]=(_Float16)v0_.w;                   \
            p0_[4]=(_Float16)v1_.x; p0_[5]=(_Float16)v1_.y;                   \
            p0_[6]=(_Float16)v1_.z; p0_[7]=(_Float16)v1_.w;                   \
            p1_[0]=(_Float16)v2_.x; p1_[1]=(_Float16)v2_.y;                   \
            p1_[2]=(_Float16)v2_.z; p1_[3]=(_Float16)v2_.w;                   \
            p1_[4]=(_Float16)v3_.x; p1_[5]=(_Float16)v3_.y;                   \
            p1_[6]=(_Float16)v3_.z; p1_[7]=(_Float16)v3_.w;                   \
            f16x8* dst_ = (f16x8*)&SH1[staged&1][0][0];                       \
            dst_[2*l] = p0_; dst_[2*l+1] = p1_;                               \
            asm volatile("" ::: "memory");                                    \
            if (l == 0){                                                      \
              __hip_atomic_store(&consFlag[bb], staged + 1u,                  \
                  __ATOMIC_RELAXED, __HIP_MEMORY_SCOPE_AGENT);                \
              readyUpTo = staged + 1u;                                        \
            }                                                                 \
            staged++;                                                         \
          }                                                                   \
        }                                                                     \
      } while(0)

    #pragma unroll 1
    for (int m = 0; m < TB; ++m){
      const int c = m >> 3;
      if ((m & 7) == 0){
        int gd = 0;
        while (*(volatile unsigned*)&readyUpTo < (unsigned)(c + 1)
               && gd++ < (1 << 20)){
          if (w == 4) STAGE_ATTEMPT();
          __syncthreads();
        }
        if (w == 4) STAGE_ATTEMPT();   // opportunistic prefetch of chunk c+1
      }

      if (w < 4){
        const f16x8* pA2 = (const f16x8*)&H2R[(m+7)&7][0];     // h2(m-1)
        const f16x8 a20 = pA2[quad], a21 = pA2[4+quad];
        const f16x8* pA1 = (const f16x8*)&SH1[c&1][m&7][0];    // staged h1(m)
        const f16x8 a10 = pA1[quad],    a11 = pA1[4+quad],
                    a12 = pA1[8+quad],  a13 = pA1[12+quad];
        f32x4 lo[4], hi[4];
        #pragma unroll
        for (int g = 0; g < 4; ++g){
          lo[g] = MFMA16(a10, B2i[4*g+0], zacc);
          hi[g] = MFMA16(a12, B2i[4*g+2], zacc);
        }
        #pragma unroll
        for (int g = 0; g < 4; ++g){
          lo[g] = MFMA16(a11, B2i[4*g+1], lo[g]);
          hi[g] = MFMA16(a13, B2i[4*g+3], hi[g]);
        }
        #pragma unroll
        for (int g = 0; g < 4; ++g){
          lo[g] = MFMA16(a20, B2h[2*g+0], lo[g]);
          hi[g] = MFMA16(a21, B2h[2*g+1], hi[g]);
        }
        if (l < 16){
          float g4[4];
          #pragma unroll
          for (int g = 0; g < 4; ++g) g4[g] = lo[g][0] + hi[g][0] + biasB[g];
          c2 = sigmoid_f(g4[1]) * c2 + sigmoid_f(g4[0]) * tanh_f(g4[2]);
          const float hv = sigmoid_f(g4[3]) * tanh_f(c2);
          if (m < TB-1) H2R[m&7][16*w + l] = (_Float16)hv;
          else          out[bb * EMB2 + 16*w + l] = hv;
        }
      }
      __syncthreads();
    }
    #undef STAGE_ATTEMPT
  }
}

extern "C" void kernel_launch(void* const* d_in, const int* in_sizes, int n_in,
                              void* d_out, int out_size, void* d_ws, size_t ws_size,
                              hipStream_t stream) {
  // zero the 256 flag counters each launch (stream-ordered, graph-capturable)
  hipMemsetAsync(d_ws, 0, 256 * sizeof(unsigned), stream);
  lstm2_kernel<<<dim3(256), dim3(512), 0, stream>>>(
      (const float*)d_in[0],   // x
      (const float*)d_in[1],   // w_ih1
      (const float*)d_in[2],   // w_hh1
      (const float*)d_in[3],   // b_ih1
      (const float*)d_in[4],   // b_hh1
      (const float*)d_in[5],   // w_ih2
      (const float*)d_in[6],   // w_hh2
      (const float*)d_in[7],   // b_ih2
      (const float*)d_in[8],   // b_hh2
      (float*)d_out,
      (unsigned*)d_ws);
}